// Round 6
// baseline (365.117 us; speedup 1.0000x reference)
//
#include <hip/hip_runtime.h>
#include <hip/hip_bf16.h>

// GraphSAGE 2-layer forward — CSR-gather + bf16 MFMA, fused pipeline (R6).
//   k1: hist(deg) + weight prep (fused)
//   k2: chained-prefix scan -> off, cursor (1 kernel, flag chain)
//   k3: gemm1 (x -> zl1|zr1, bf16 MFMA) + fill_csr (fused, extra blocks)
//   k4: fused mid: h=sigmoid(mean(zl1)+zr1+b1) in LDS -> gemm2 -> zl2|zr2
//   k5: agg2: out = mean(ql) + qr + b2   (fp32)

#define N_FEAT 128
#define HID 64
#define NCLS 40
#define SENTINEL ((int)0xAAAAAAAA)

typedef short short8 __attribute__((ext_vector_type(8)));
typedef float floatx4 __attribute__((ext_vector_type(4)));

static __device__ __forceinline__ short f2bf(float x) {
    __hip_bfloat16 h = __float2bfloat16(x);
    return __builtin_bit_cast(short, h);
}
static __device__ __forceinline__ float bf2f(unsigned short u) {
    unsigned int v = ((unsigned int)u) << 16;
    return __builtin_bit_cast(float, v);
}

// ---------------------------------------------------------------------------
// k1: histogram of dst degrees + weight transpose/cvt (independent blocks)
// ---------------------------------------------------------------------------
__global__ void hist_prep(const int* __restrict__ ei, int* __restrict__ deg,
                          int ne, int histBlocks,
                          const float* __restrict__ W1l, const float* __restrict__ W1r,
                          const float* __restrict__ W2l, const float* __restrict__ W2r,
                          unsigned short* __restrict__ wt1,
                          unsigned short* __restrict__ wt2) {
    if ((int)blockIdx.x < histBlocks) {
        int e = blockIdx.x * 256 + threadIdx.x;
        if (e < ne) atomicAdd(&deg[ei[ne + e]], 1);
    } else {
        int i = (blockIdx.x - histBlocks) * 256 + threadIdx.x;
        if (i < 128 * 128) {
            int nn = i >> 7, k = i & 127;
            float v = (nn < 64) ? W1l[k * 64 + nn] : W1r[k * 64 + (nn - 64)];
            wt1[nn * 128 + k] = (unsigned short)f2bf(v);
        } else if (i < 128 * 128 + 80 * 64) {
            int j = i - 128 * 128;
            int nn = j >> 6, k = j & 63;
            float v = (nn < 40) ? W2l[k * 40 + nn] : W2r[k * 40 + (nn - 40)];
            wt2[nn * 64 + k] = (unsigned short)f2bf(v);
        }
    }
}

// ---------------------------------------------------------------------------
// k2: single-kernel exclusive scan (chained prefixes). Block b scans its
// 2048-chunk, waits for block b-1's published prefix (flags, sentinel=0xAA),
// publishes its own, writes off[] and cursor[]. 49 blocks -> co-resident.
// ---------------------------------------------------------------------------
__global__ void scan_chain(const int* __restrict__ deg, int* __restrict__ off,
                           int* __restrict__ cursor, int* __restrict__ flags,
                           int n) {
    __shared__ int lds[256];
    __shared__ int sprefix;
    const int b = blockIdx.x, t = threadIdx.x;
    const int base = b * 2048 + t * 8;
    int v[8], s = 0;
#pragma unroll
    for (int i = 0; i < 8; ++i) {
        int idx = base + i;
        v[i] = (idx < n) ? deg[idx] : 0;
        s += v[i];
    }
    lds[t] = s;
    __syncthreads();
    for (int o = 1; o < 256; o <<= 1) {
        int y = (t >= o) ? lds[t - o] : 0;
        __syncthreads();
        lds[t] += y;
        __syncthreads();
    }
    const int total = lds[255];
    if (t == 0) {
        int p = 0;
        if (b > 0) {
            do {
                p = __hip_atomic_load(&flags[b - 1], __ATOMIC_ACQUIRE,
                                      __HIP_MEMORY_SCOPE_AGENT);
            } while (p == SENTINEL);
        }
        __hip_atomic_store(&flags[b], p + total, __ATOMIC_RELEASE,
                           __HIP_MEMORY_SCOPE_AGENT);
        sprefix = p;
    }
    __syncthreads();
    const int prefix = sprefix;
    int run = prefix + ((t == 0) ? 0 : lds[t - 1]);
#pragma unroll
    for (int i = 0; i < 8; ++i) {
        run += v[i];
        int idx = base + i;
        if (idx < n) {
            off[idx + 1] = run;
            cursor[idx + 1] = run;
        }
    }
    if (b == 0 && t == 0) {
        off[0] = 0;
        cursor[0] = 0;
    }
}

// ---------------------------------------------------------------------------
// k3: gemm1 (MFMA) + fill_csr fused. Blocks [0,gB): GEMM 64 rows each;
// blocks [gB,..): scatter edges into csr via cursor atomics.
// ---------------------------------------------------------------------------
__global__ __launch_bounds__(256) void gemm1_fill(
    const float* __restrict__ x, const unsigned short* __restrict__ wt1,
    unsigned short* __restrict__ Zl, unsigned short* __restrict__ Zr, int n,
    const int* __restrict__ ei, int* __restrict__ cursor, int* __restrict__ csr,
    int ne, int gB) {
    constexpr int K = N_FEAT;        // 128
    constexpr int M = 2 * HID;       // 128
    constexpr int LDA = K + 8;
    constexpr int QROW = K / 8;
    __shared__ __align__(16) short At[64 * LDA];
    __shared__ __align__(16) short Bt[M * LDA];

    const int t = threadIdx.x;
    if ((int)blockIdx.x >= gB) {
        int e = (blockIdx.x - gB) * 256 + t;
        if (e < ne) {
            int d = ei[ne + e];
            int p = atomicAdd(&cursor[d], 1);
            csr[p] = ei[e];
        }
        return;
    }

    const int nodeBase = blockIdx.x * 64;
    for (int q = t; q < 64 * QROW; q += 256) {
        int row = q / QROW;
        int k0 = (q % QROW) * 8;
        int node = nodeBase + row;
        short8 s = {0, 0, 0, 0, 0, 0, 0, 0};
        if (node < n) {
            const float* A = x + (size_t)node * K + k0;
            float4 v0 = *(const float4*)A;
            float4 v1 = *(const float4*)(A + 4);
            s[0] = f2bf(v0.x); s[1] = f2bf(v0.y);
            s[2] = f2bf(v0.z); s[3] = f2bf(v0.w);
            s[4] = f2bf(v1.x); s[5] = f2bf(v1.y);
            s[6] = f2bf(v1.z); s[7] = f2bf(v1.w);
        }
        *(short8*)&At[row * LDA + k0] = s;
    }
    for (int q = t; q < M * QROW; q += 256) {
        int row = q / QROW;
        int k0 = (q % QROW) * 8;
        *(short8*)&Bt[row * LDA + k0] =
            *(const short8*)&wt1[(size_t)row * K + k0];
    }
    __syncthreads();

    const int wave = t >> 6;
    const int lane = t & 63;
    const int m0 = wave * 16;
    const int fl = lane & 15;
    const int quad = lane >> 4;

    floatx4 acc[M / 16];
#pragma unroll
    for (int nt = 0; nt < M / 16; ++nt) acc[nt] = (floatx4){0.f, 0.f, 0.f, 0.f};

#pragma unroll
    for (int ks = 0; ks < K / 32; ++ks) {
        const int kb = ks * 32 + quad * 8;
        short8 a = *(const short8*)&At[(m0 + fl) * LDA + kb];
#pragma unroll
        for (int nt = 0; nt < M / 16; ++nt) {
            short8 b = *(const short8*)&Bt[(nt * 16 + fl) * LDA + kb];
            acc[nt] = __builtin_amdgcn_mfma_f32_16x16x32_bf16(a, b, acc[nt], 0, 0, 0);
        }
    }

#pragma unroll
    for (int nt = 0; nt < M / 16; ++nt) {
        const int col = nt * 16 + fl;
#pragma unroll
        for (int r = 0; r < 4; ++r) {
            int node = nodeBase + m0 + quad * 4 + r;
            if (node < n) {
                unsigned short v = (unsigned short)f2bf(acc[nt][r]);
                if (col < HID)
                    Zl[(size_t)node * HID + col] = v;
                else
                    Zr[(size_t)node * HID + (col - HID)] = v;
            }
        }
    }
}

// ---------------------------------------------------------------------------
// k4: fused mid. Block = 64 nodes, 4 waves. Wave aggregates 16 nodes
// (2 in flight x 8-deep gather batches), computes h = sigmoid(mean+zr+b1),
// stores bf16 to LDS A-tile; then in-block MFMA with wt2 -> zl2|zr2.
// ---------------------------------------------------------------------------
__global__ __launch_bounds__(256) void fused_mid(
    const unsigned short* __restrict__ zl1, const unsigned short* __restrict__ zr1,
    const int* __restrict__ off, const int* __restrict__ csr,
    const float* __restrict__ b1, const unsigned short* __restrict__ wt2,
    unsigned short* __restrict__ zl2, unsigned short* __restrict__ zr2, int n) {
    constexpr int LDH = HID + 8;  // 72
    __shared__ __align__(16) short Ht[64 * LDH];
    __shared__ __align__(16) short Bt[80 * LDH];

    const int t = threadIdx.x;
    const int wave = t >> 6;
    const int lane = t & 63;
    const int nodeBase = blockIdx.x * 64;

    // stage wt2 (80 x 64)
    for (int q = t; q < 80 * 8; q += 256) {
        int row = q >> 3;
        int k0 = (q & 7) * 8;
        *(short8*)&Bt[row * LDH + k0] = *(const short8*)&wt2[row * 64 + k0];
    }
    const float bs = b1[lane];

    for (int i = 0; i < 16; i += 2) {
        const int loc0 = wave * 16 + i, loc1 = loc0 + 1;
        const int node0 = nodeBase + loc0, node1 = nodeBase + loc1;
        const bool ok0 = node0 < n, ok1 = node1 < n;
        int s0 = 0, e0 = 0, s1 = 0, e1 = 0;
        if (ok0) { s0 = off[node0]; e0 = off[node0 + 1]; }
        if (ok1) { s1 = off[node1]; e1 = off[node1 + 1]; }
        float acc0 = 0.f, acc1 = 0.f;
        for (int e = 0;; e += 8) {
            const bool need0 = s0 + e < e0, need1 = s1 + e < e1;
            if (!need0 && !need1) break;
            int idx[16];
            float v[16];
#pragma unroll
            for (int j = 0; j < 8; ++j) {
                int ee = s0 + e + j;
                ee = (ee < e0) ? ee : (e0 - 1);
                idx[j] = need0 ? csr[ee] : 0;
            }
#pragma unroll
            for (int j = 0; j < 8; ++j) {
                int ee = s1 + e + j;
                ee = (ee < e1) ? ee : (e1 - 1);
                idx[8 + j] = need1 ? csr[ee] : 0;
            }
#pragma unroll
            for (int j = 0; j < 16; ++j)
                v[j] = bf2f(zl1[(size_t)idx[j] * HID + lane]);
#pragma unroll
            for (int j = 0; j < 8; ++j)
                acc0 += (s0 + e + j < e0) ? v[j] : 0.f;
#pragma unroll
            for (int j = 0; j < 8; ++j)
                acc1 += (s1 + e + j < e1) ? v[8 + j] : 0.f;
        }
        float r0 = 0.f, r1 = 0.f;
        if (ok0) {
            float inv = 1.0f / fmaxf((float)(e0 - s0), 1.0f);
            r0 = acc0 * inv + bf2f(zr1[(size_t)node0 * HID + lane]) + bs;
            r0 = 1.0f / (1.0f + __expf(-r0));
        }
        if (ok1) {
            float inv = 1.0f / fmaxf((float)(e1 - s1), 1.0f);
            r1 = acc1 * inv + bf2f(zr1[(size_t)node1 * HID + lane]) + bs;
            r1 = 1.0f / (1.0f + __expf(-r1));
        }
        Ht[loc0 * LDH + lane] = f2bf(r0);
        Ht[loc1 * LDH + lane] = f2bf(r1);
    }
    __syncthreads();

    // in-block gemm2: [64 x 64] @ [64 x 80]^T
    const int m0 = wave * 16;
    const int fl = lane & 15;
    const int quad = lane >> 4;
    floatx4 acc[5];
#pragma unroll
    for (int nt = 0; nt < 5; ++nt) acc[nt] = (floatx4){0.f, 0.f, 0.f, 0.f};
#pragma unroll
    for (int ks = 0; ks < 2; ++ks) {
        const int kb = ks * 32 + quad * 8;
        short8 a = *(const short8*)&Ht[(m0 + fl) * LDH + kb];
#pragma unroll
        for (int nt = 0; nt < 5; ++nt) {
            short8 b = *(const short8*)&Bt[(nt * 16 + fl) * LDH + kb];
            acc[nt] = __builtin_amdgcn_mfma_f32_16x16x32_bf16(a, b, acc[nt], 0, 0, 0);
        }
    }
#pragma unroll
    for (int nt = 0; nt < 5; ++nt) {
        const int col = nt * 16 + fl;
#pragma unroll
        for (int r = 0; r < 4; ++r) {
            int node = nodeBase + m0 + quad * 4 + r;
            if (node < n) {
                unsigned short v = (unsigned short)f2bf(acc[nt][r]);
                if (col < NCLS)
                    zl2[(size_t)node * NCLS + col] = v;
                else
                    zr2[(size_t)node * NCLS + (col - NCLS)] = v;
            }
        }
    }
}

// ---------------------------------------------------------------------------
// k5: final aggregate. One wave per node, lane = feature (40), batched 8.
// ---------------------------------------------------------------------------
__global__ void agg_out(const unsigned short* __restrict__ Zl,
                        const unsigned short* __restrict__ Zr,
                        const int* __restrict__ off,
                        const int* __restrict__ csr,
                        const float* __restrict__ bias,
                        float* __restrict__ out, int n) {
    const int node = blockIdx.x * (blockDim.x >> 6) + (threadIdx.x >> 6);
    const int lane = threadIdx.x & 63;
    if (node >= n) return;
    const int start = off[node];
    const int end = off[node + 1];
    if (lane < NCLS) {
        float acc = 0.f;
        for (int e = start; e < end; e += 8) {
            int idx[8];
            float v[8];
#pragma unroll
            for (int i = 0; i < 8; ++i) {
                int ee = (e + i < end) ? (e + i) : (end - 1);
                idx[i] = csr[ee];
            }
#pragma unroll
            for (int i = 0; i < 8; ++i)
                v[i] = bf2f(Zl[(size_t)idx[i] * NCLS + lane]);
#pragma unroll
            for (int i = 0; i < 8; ++i)
                acc += (e + i < end) ? v[i] : 0.f;
        }
        float inv = 1.0f / fmaxf((float)(end - start), 1.0f);
        float r = acc * inv + bf2f(Zr[(size_t)node * NCLS + lane]) + bias[lane];
        out[(size_t)node * NCLS + lane] = r;
    }
}

// ---------------------------------------------------------------------------
extern "C" void kernel_launch(void* const* d_in, const int* in_sizes, int n_in,
                              void* d_out, int out_size, void* d_ws,
                              size_t ws_size, hipStream_t stream) {
    const float* x = (const float*)d_in[0];
    const int* ei = (const int*)d_in[1];
    const float* W1l = (const float*)d_in[2];
    const float* b1 = (const float*)d_in[3];
    const float* W1r = (const float*)d_in[4];
    const float* W2l = (const float*)d_in[5];
    const float* b2 = (const float*)d_in[6];
    const float* W2r = (const float*)d_in[7];
    float* out = (float*)d_out;

    const int n = in_sizes[0] / N_FEAT;  // 100000
    const int ne = in_sizes[1] / 2;      // 600000

    // ws: zl1|zr1 [n*64] | zl2|zr2 [n*40] | wt1 | wt2 | deg | off | cursor |
    //     csr | flags
    unsigned short* zl1 = (unsigned short*)d_ws;
    unsigned short* zr1 = zl1 + (size_t)n * HID;
    unsigned short* zl2 = zr1 + (size_t)n * HID;
    unsigned short* zr2 = zl2 + (size_t)n * NCLS;
    unsigned short* wt1 = zr2 + (size_t)n * NCLS;
    unsigned short* wt2 = wt1 + 128 * 128;
    int* deg = (int*)(wt2 + 80 * 64);
    int* off = deg + n;
    int* cursor = off + (n + 1);
    int* csr = cursor + (n + 1);
    int* flags = csr + ne;

    const int nb = (n + 2047) / 2048;          // 49
    const int histB = (ne + 255) / 256;        // 2344
    const int prepB = (128 * 128 + 80 * 64) / 256;  // 84
    const int gB = (n + 63) / 64;              // 1563
    const int fillB = (ne + 255) / 256;

    hipMemsetAsync(deg, 0, (size_t)n * sizeof(int), stream);
    hipMemsetAsync(flags, 0xAA, (size_t)nb * sizeof(int), stream);

    hist_prep<<<histB + prepB, 256, 0, stream>>>(ei, deg, ne, histB, W1l, W1r,
                                                 W2l, W2r, wt1, wt2);
    scan_chain<<<nb, 256, 0, stream>>>(deg, off, cursor, flags, n);
    gemm1_fill<<<gB + fillB, 256, 0, stream>>>(x, wt1, zl1, zr1, n, ei, cursor,
                                               csr, ne, gB);
    fused_mid<<<gB, 256, 0, stream>>>(zl1, zr1, off, csr, b1, wt2, zl2, zr2, n);
    agg_out<<<(n + 3) / 4, 256, 0, stream>>>(zl2, zr2, off, csr, b2, out, n);
}

// Round 7
// 309.850 us; speedup vs baseline: 1.1784x; 1.1784x over previous
//
#include <hip/hip_runtime.h>
#include <hip/hip_bf16.h>

// GraphSAGE 2-layer forward — CSR-gather + bf16 MFMA (R7).
// R6 post-mortem: fusing agg1+gemm2 serialized 16 latency-bound node-gathers
// per wave behind a block barrier (110 us vs 42 us separate) — reverted.
// Kept: hist+prep fusion, single-kernel chained scan, fill_csr under gemm1.
//   k1: hist(deg) + weight prep
//   k2: chained-prefix scan -> off, cursor
//   k3: gemm1 (x -> zl1|zr1, MFMA) + fill_csr (extra blocks)
//   k4: agg1: h = sigmoid(mean(zl1)+zr1+b1)   (1 node/wave, 8-deep batches)
//   k5: gemm2 (h -> zl2|zr2, MFMA)
//   k6: agg2: out = mean(zl2)+zr2+b2  (fp32)

#define N_FEAT 128
#define HID 64
#define NCLS 40
#define SENTINEL ((int)0xAAAAAAAA)

typedef short short8 __attribute__((ext_vector_type(8)));
typedef float floatx4 __attribute__((ext_vector_type(4)));

static __device__ __forceinline__ short f2bf(float x) {
    __hip_bfloat16 h = __float2bfloat16(x);
    return __builtin_bit_cast(short, h);
}
static __device__ __forceinline__ float bf2f(unsigned short u) {
    unsigned int v = ((unsigned int)u) << 16;
    return __builtin_bit_cast(float, v);
}

// ---------------------------------------------------------------------------
// k1: histogram of dst degrees + weight transpose/cvt (independent blocks)
// ---------------------------------------------------------------------------
__global__ void hist_prep(const int* __restrict__ ei, int* __restrict__ deg,
                          int ne, int histBlocks,
                          const float* __restrict__ W1l, const float* __restrict__ W1r,
                          const float* __restrict__ W2l, const float* __restrict__ W2r,
                          unsigned short* __restrict__ wt1,
                          unsigned short* __restrict__ wt2) {
    if ((int)blockIdx.x < histBlocks) {
        int e = blockIdx.x * 256 + threadIdx.x;
        if (e < ne) atomicAdd(&deg[ei[ne + e]], 1);
    } else {
        int i = (blockIdx.x - histBlocks) * 256 + threadIdx.x;
        if (i < 128 * 128) {
            int nn = i >> 7, k = i & 127;
            float v = (nn < 64) ? W1l[k * 64 + nn] : W1r[k * 64 + (nn - 64)];
            wt1[nn * 128 + k] = (unsigned short)f2bf(v);
        } else if (i < 128 * 128 + 80 * 64) {
            int j = i - 128 * 128;
            int nn = j >> 6, k = j & 63;
            float v = (nn < 40) ? W2l[k * 40 + nn] : W2r[k * 40 + (nn - 40)];
            wt2[nn * 64 + k] = (unsigned short)f2bf(v);
        }
    }
}

// ---------------------------------------------------------------------------
// k2: single-kernel exclusive scan (chained prefixes). Block b scans its
// 2048-chunk, spins on block b-1's published prefix (sentinel = 0xAAAAAAAA,
// ws re-poisoned each call; prefixes <= 600000 never alias), publishes its
// own, writes off[] and cursor[]. 49 blocks -> co-resident, no deadlock.
// ---------------------------------------------------------------------------
__global__ void scan_chain(const int* __restrict__ deg, int* __restrict__ off,
                           int* __restrict__ cursor, int* __restrict__ flags,
                           int n) {
    __shared__ int lds[256];
    __shared__ int sprefix;
    const int b = blockIdx.x, t = threadIdx.x;
    const int base = b * 2048 + t * 8;
    int v[8], s = 0;
#pragma unroll
    for (int i = 0; i < 8; ++i) {
        int idx = base + i;
        v[i] = (idx < n) ? deg[idx] : 0;
        s += v[i];
    }
    lds[t] = s;
    __syncthreads();
    for (int o = 1; o < 256; o <<= 1) {
        int y = (t >= o) ? lds[t - o] : 0;
        __syncthreads();
        lds[t] += y;
        __syncthreads();
    }
    const int total = lds[255];
    if (t == 0) {
        int p = 0;
        if (b > 0) {
            do {
                p = __hip_atomic_load(&flags[b - 1], __ATOMIC_ACQUIRE,
                                      __HIP_MEMORY_SCOPE_AGENT);
            } while (p == SENTINEL);
        }
        __hip_atomic_store(&flags[b], p + total, __ATOMIC_RELEASE,
                           __HIP_MEMORY_SCOPE_AGENT);
        sprefix = p;
    }
    __syncthreads();
    const int prefix = sprefix;
    int run = prefix + ((t == 0) ? 0 : lds[t - 1]);
#pragma unroll
    for (int i = 0; i < 8; ++i) {
        run += v[i];
        int idx = base + i;
        if (idx < n) {
            off[idx + 1] = run;
            cursor[idx + 1] = run;
        }
    }
    if (b == 0 && t == 0) {
        off[0] = 0;
        cursor[0] = 0;
    }
}

// ---------------------------------------------------------------------------
// k3: gemm1 (MFMA) + fill_csr fused (scatter hides under GEMM blocks).
// ---------------------------------------------------------------------------
__global__ __launch_bounds__(256) void gemm1_fill(
    const float* __restrict__ x, const unsigned short* __restrict__ wt1,
    unsigned short* __restrict__ Zl, unsigned short* __restrict__ Zr, int n,
    const int* __restrict__ ei, int* __restrict__ cursor, int* __restrict__ csr,
    int ne, int gB) {
    constexpr int K = N_FEAT;   // 128
    constexpr int M = 2 * HID;  // 128
    constexpr int LDA = K + 8;
    constexpr int QROW = K / 8;
    __shared__ __align__(16) short At[64 * LDA];
    __shared__ __align__(16) short Bt[M * LDA];

    const int t = threadIdx.x;
    if ((int)blockIdx.x >= gB) {
        int e = (blockIdx.x - gB) * 256 + t;
        if (e < ne) {
            int d = ei[ne + e];
            int p = atomicAdd(&cursor[d], 1);
            csr[p] = ei[e];
        }
        return;
    }

    const int nodeBase = blockIdx.x * 64;
    for (int q = t; q < 64 * QROW; q += 256) {
        int row = q / QROW;
        int k0 = (q % QROW) * 8;
        int node = nodeBase + row;
        short8 s = {0, 0, 0, 0, 0, 0, 0, 0};
        if (node < n) {
            const float* A = x + (size_t)node * K + k0;
            float4 v0 = *(const float4*)A;
            float4 v1 = *(const float4*)(A + 4);
            s[0] = f2bf(v0.x); s[1] = f2bf(v0.y);
            s[2] = f2bf(v0.z); s[3] = f2bf(v0.w);
            s[4] = f2bf(v1.x); s[5] = f2bf(v1.y);
            s[6] = f2bf(v1.z); s[7] = f2bf(v1.w);
        }
        *(short8*)&At[row * LDA + k0] = s;
    }
    for (int q = t; q < M * QROW; q += 256) {
        int row = q / QROW;
        int k0 = (q % QROW) * 8;
        *(short8*)&Bt[row * LDA + k0] =
            *(const short8*)&wt1[(size_t)row * K + k0];
    }
    __syncthreads();

    const int wave = t >> 6;
    const int lane = t & 63;
    const int m0 = wave * 16;
    const int fl = lane & 15;
    const int quad = lane >> 4;

    floatx4 acc[M / 16];
#pragma unroll
    for (int nt = 0; nt < M / 16; ++nt) acc[nt] = (floatx4){0.f, 0.f, 0.f, 0.f};

#pragma unroll
    for (int ks = 0; ks < K / 32; ++ks) {
        const int kb = ks * 32 + quad * 8;
        short8 a = *(const short8*)&At[(m0 + fl) * LDA + kb];
#pragma unroll
        for (int nt = 0; nt < M / 16; ++nt) {
            short8 b = *(const short8*)&Bt[(nt * 16 + fl) * LDA + kb];
            acc[nt] = __builtin_amdgcn_mfma_f32_16x16x32_bf16(a, b, acc[nt], 0, 0, 0);
        }
    }

#pragma unroll
    for (int nt = 0; nt < M / 16; ++nt) {
        const int col = nt * 16 + fl;
#pragma unroll
        for (int r = 0; r < 4; ++r) {
            int node = nodeBase + m0 + quad * 4 + r;
            if (node < n) {
                unsigned short v = (unsigned short)f2bf(acc[nt][r]);
                if (col < HID)
                    Zl[(size_t)node * HID + col] = v;
                else
                    Zr[(size_t)node * HID + (col - HID)] = v;
            }
        }
    }
}

// ---------------------------------------------------------------------------
// k5: gemm2 (MFMA): h -> zl2|zr2 split packed. Same structure, K=64, M=80.
// ---------------------------------------------------------------------------
__global__ __launch_bounds__(256) void gemm2_mfma(
    const unsigned short* __restrict__ h, const unsigned short* __restrict__ wt2,
    unsigned short* __restrict__ Zl, unsigned short* __restrict__ Zr, int n) {
    constexpr int K = HID;       // 64
    constexpr int M = 2 * NCLS;  // 80
    constexpr int LDA = K + 8;
    constexpr int QROW = K / 8;
    __shared__ __align__(16) short At[64 * LDA];
    __shared__ __align__(16) short Bt[M * LDA];

    const int t = threadIdx.x;
    const int nodeBase = blockIdx.x * 64;

    for (int q = t; q < 64 * QROW; q += 256) {
        int row = q / QROW;
        int k0 = (q % QROW) * 8;
        int node = nodeBase + row;
        short8 s = {0, 0, 0, 0, 0, 0, 0, 0};
        if (node < n)
            s = *(const short8*)((const short*)h + (size_t)node * K + k0);
        *(short8*)&At[row * LDA + k0] = s;
    }
    for (int q = t; q < M * QROW; q += 256) {
        int row = q / QROW;
        int k0 = (q % QROW) * 8;
        *(short8*)&Bt[row * LDA + k0] =
            *(const short8*)&wt2[(size_t)row * K + k0];
    }
    __syncthreads();

    const int wave = t >> 6;
    const int lane = t & 63;
    const int m0 = wave * 16;
    const int fl = lane & 15;
    const int quad = lane >> 4;

    floatx4 acc[M / 16];
#pragma unroll
    for (int nt = 0; nt < M / 16; ++nt) acc[nt] = (floatx4){0.f, 0.f, 0.f, 0.f};

#pragma unroll
    for (int ks = 0; ks < K / 32; ++ks) {
        const int kb = ks * 32 + quad * 8;
        short8 a = *(const short8*)&At[(m0 + fl) * LDA + kb];
#pragma unroll
        for (int nt = 0; nt < M / 16; ++nt) {
            short8 b = *(const short8*)&Bt[(nt * 16 + fl) * LDA + kb];
            acc[nt] = __builtin_amdgcn_mfma_f32_16x16x32_bf16(a, b, acc[nt], 0, 0, 0);
        }
    }

#pragma unroll
    for (int nt = 0; nt < M / 16; ++nt) {
        const int col = nt * 16 + fl;
#pragma unroll
        for (int r = 0; r < 4; ++r) {
            int node = nodeBase + m0 + quad * 4 + r;
            if (node < n) {
                unsigned short v = (unsigned short)f2bf(acc[nt][r]);
                if (col < NCLS)
                    Zl[(size_t)node * NCLS + col] = v;
                else
                    Zr[(size_t)node * NCLS + (col - NCLS)] = v;
            }
        }
    }
}

// ---------------------------------------------------------------------------
// agg: one wave per node, lane = feature, 8-deep gather batches (max TLP —
// do NOT serialize multiple nodes per wave; see R6 post-mortem).
// ---------------------------------------------------------------------------
template <int F, bool SIG, bool OUTBF>
__global__ void agg_kernel(const unsigned short* __restrict__ Zl,
                           const unsigned short* __restrict__ Zr,
                           const int* __restrict__ off,
                           const int* __restrict__ csr,
                           const float* __restrict__ bias,
                           void* __restrict__ out, int n) {
    const int node = blockIdx.x * (blockDim.x >> 6) + (threadIdx.x >> 6);
    const int lane = threadIdx.x & 63;
    if (node >= n) return;
    const int start = off[node];
    const int end = off[node + 1];
    if (lane < F) {
        float acc = 0.f;
        for (int e = start; e < end; e += 8) {
            int idx[8];
            float v[8];
#pragma unroll
            for (int i = 0; i < 8; ++i) {
                int ee = (e + i < end) ? (e + i) : (end - 1);
                idx[i] = csr[ee];
            }
#pragma unroll
            for (int i = 0; i < 8; ++i)
                v[i] = bf2f(Zl[(size_t)idx[i] * F + lane]);
#pragma unroll
            for (int i = 0; i < 8; ++i)
                acc += (e + i < end) ? v[i] : 0.f;
        }
        float inv = 1.0f / fmaxf((float)(end - start), 1.0f);
        float r = acc * inv + bf2f(Zr[(size_t)node * F + lane]) + bias[lane];
        if (SIG) r = 1.0f / (1.0f + __expf(-r));
        if (OUTBF)
            ((unsigned short*)out)[(size_t)node * F + lane] = (unsigned short)f2bf(r);
        else
            ((float*)out)[(size_t)node * F + lane] = r;
    }
}

// ---------------------------------------------------------------------------
extern "C" void kernel_launch(void* const* d_in, const int* in_sizes, int n_in,
                              void* d_out, int out_size, void* d_ws,
                              size_t ws_size, hipStream_t stream) {
    const float* x = (const float*)d_in[0];
    const int* ei = (const int*)d_in[1];
    const float* W1l = (const float*)d_in[2];
    const float* b1 = (const float*)d_in[3];
    const float* W1r = (const float*)d_in[4];
    const float* W2l = (const float*)d_in[5];
    const float* b2 = (const float*)d_in[6];
    const float* W2r = (const float*)d_in[7];
    float* out = (float*)d_out;

    const int n = in_sizes[0] / N_FEAT;  // 100000
    const int ne = in_sizes[1] / 2;      // 600000

    // ws: zl1|zr1 [n*64] | h [n*64] | zl2|zr2 [n*40] | wt1 | wt2 |
    //     deg | off | cursor | csr | flags
    unsigned short* zl1 = (unsigned short*)d_ws;
    unsigned short* zr1 = zl1 + (size_t)n * HID;
    unsigned short* h = zr1 + (size_t)n * HID;
    unsigned short* zl2 = h + (size_t)n * HID;
    unsigned short* zr2 = zl2 + (size_t)n * NCLS;
    unsigned short* wt1 = zr2 + (size_t)n * NCLS;
    unsigned short* wt2 = wt1 + 128 * 128;
    int* deg = (int*)(wt2 + 80 * 64);
    int* off = deg + n;
    int* cursor = off + (n + 1);
    int* csr = cursor + (n + 1);
    int* flags = csr + ne;

    const int nb = (n + 2047) / 2048;               // 49
    const int histB = (ne + 255) / 256;             // 2344
    const int prepB = (128 * 128 + 80 * 64) / 256;  // 84
    const int gB = (n + 63) / 64;                   // 1563
    const int fillB = (ne + 255) / 256;
    const int aB = (n + 3) / 4;

    hipMemsetAsync(deg, 0, (size_t)n * sizeof(int), stream);
    hipMemsetAsync(flags, 0xAA, (size_t)nb * sizeof(int), stream);

    hist_prep<<<histB + prepB, 256, 0, stream>>>(ei, deg, ne, histB, W1l, W1r,
                                                 W2l, W2r, wt1, wt2);
    scan_chain<<<nb, 256, 0, stream>>>(deg, off, cursor, flags, n);
    gemm1_fill<<<gB + fillB, 256, 0, stream>>>(x, wt1, zl1, zr1, n, ei, cursor,
                                               csr, ne, gB);
    agg_kernel<HID, true, true>
        <<<aB, 256, 0, stream>>>(zl1, zr1, off, csr, b1, h, n);
    gemm2_mfma<<<gB, 256, 0, stream>>>(h, wt2, zl2, zr2, n);
    agg_kernel<NCLS, false, false>
        <<<aB, 256, 0, stream>>>(zl2, zr2, off, csr, b2, out, n);
}

// Round 8
// 302.624 us; speedup vs baseline: 1.2065x; 1.0239x over previous
//
#include <hip/hip_runtime.h>
#include <hip/hip_bf16.h>

// GraphSAGE 2-layer forward — CSR-gather + bf16 MFMA (R8).
// R6 lesson: don't serialize latency-bound node-gathers behind block barriers.
// R7 lesson: don't fuse no-LDS scatter blocks into a 52KB-LDS kernel — the
// LDS reservation cuts the scatter's occupancy 32->12 waves/CU (76us kernel).
// Structure: memset x2 -> hist+prep -> chained scan -> fill_csr -> gemm1 ->
//            agg1 -> gemm2 -> agg2.

#define N_FEAT 128
#define HID 64
#define NCLS 40
#define SENTINEL ((int)0xAAAAAAAA)

typedef short short8 __attribute__((ext_vector_type(8)));
typedef float floatx4 __attribute__((ext_vector_type(4)));

static __device__ __forceinline__ short f2bf(float x) {
    __hip_bfloat16 h = __float2bfloat16(x);
    return __builtin_bit_cast(short, h);
}
static __device__ __forceinline__ float bf2f(unsigned short u) {
    unsigned int v = ((unsigned int)u) << 16;
    return __builtin_bit_cast(float, v);
}

// ---------------------------------------------------------------------------
// k1: histogram of dst degrees + weight transpose/cvt (no LDS -> safe fusion)
// ---------------------------------------------------------------------------
__global__ void hist_prep(const int* __restrict__ ei, int* __restrict__ deg,
                          int ne, int histBlocks,
                          const float* __restrict__ W1l, const float* __restrict__ W1r,
                          const float* __restrict__ W2l, const float* __restrict__ W2r,
                          unsigned short* __restrict__ wt1,
                          unsigned short* __restrict__ wt2) {
    if ((int)blockIdx.x < histBlocks) {
        int e = blockIdx.x * 256 + threadIdx.x;
        if (e < ne) atomicAdd(&deg[ei[ne + e]], 1);
    } else {
        int i = (blockIdx.x - histBlocks) * 256 + threadIdx.x;
        if (i < 128 * 128) {
            int nn = i >> 7, k = i & 127;
            float v = (nn < 64) ? W1l[k * 64 + nn] : W1r[k * 64 + (nn - 64)];
            wt1[nn * 128 + k] = (unsigned short)f2bf(v);
        } else if (i < 128 * 128 + 80 * 64) {
            int j = i - 128 * 128;
            int nn = j >> 6, k = j & 63;
            float v = (nn < 40) ? W2l[k * 40 + nn] : W2r[k * 40 + (nn - 40)];
            wt2[nn * 64 + k] = (unsigned short)f2bf(v);
        }
    }
}

// ---------------------------------------------------------------------------
// k2: single-kernel exclusive scan (chained prefixes, 49 co-resident blocks).
// Sentinel = 0xAAAAAAAA (ws poison); prefixes <= 600000 never alias it.
// ---------------------------------------------------------------------------
__global__ void scan_chain(const int* __restrict__ deg, int* __restrict__ off,
                           int* __restrict__ cursor, int* __restrict__ flags,
                           int n) {
    __shared__ int lds[256];
    __shared__ int sprefix;
    const int b = blockIdx.x, t = threadIdx.x;
    const int base = b * 2048 + t * 8;
    int v[8], s = 0;
#pragma unroll
    for (int i = 0; i < 8; ++i) {
        int idx = base + i;
        v[i] = (idx < n) ? deg[idx] : 0;
        s += v[i];
    }
    lds[t] = s;
    __syncthreads();
    for (int o = 1; o < 256; o <<= 1) {
        int y = (t >= o) ? lds[t - o] : 0;
        __syncthreads();
        lds[t] += y;
        __syncthreads();
    }
    const int total = lds[255];
    if (t == 0) {
        int p = 0;
        if (b > 0) {
            do {
                p = __hip_atomic_load(&flags[b - 1], __ATOMIC_ACQUIRE,
                                      __HIP_MEMORY_SCOPE_AGENT);
            } while (p == SENTINEL);
        }
        __hip_atomic_store(&flags[b], p + total, __ATOMIC_RELEASE,
                           __HIP_MEMORY_SCOPE_AGENT);
        sprefix = p;
    }
    __syncthreads();
    const int prefix = sprefix;
    int run = prefix + ((t == 0) ? 0 : lds[t - 1]);
#pragma unroll
    for (int i = 0; i < 8; ++i) {
        run += v[i];
        int idx = base + i;
        if (idx < n) {
            off[idx + 1] = run;
            cursor[idx + 1] = run;
        }
    }
    if (b == 0 && t == 0) {
        off[0] = 0;
        cursor[0] = 0;
    }
}

// ---------------------------------------------------------------------------
// k3: fill CSR (standalone: 8 VGPR, no LDS, full occupancy)
// ---------------------------------------------------------------------------
__global__ void fill_csr(const int* __restrict__ ei, int* __restrict__ cursor,
                         int* __restrict__ csr, int ne) {
    int e = blockIdx.x * blockDim.x + threadIdx.x;
    if (e < ne) {
        int d = ei[ne + e];
        int p = atomicAdd(&cursor[d], 1);
        csr[p] = ei[e];
    }
}

// ---------------------------------------------------------------------------
// k4: gemm1 (MFMA): x (fp32, inline cvt) -> zl1|zr1 split packed bf16.
// ---------------------------------------------------------------------------
__global__ __launch_bounds__(256) void gemm1_mfma(
    const float* __restrict__ x, const unsigned short* __restrict__ wt1,
    unsigned short* __restrict__ Zl, unsigned short* __restrict__ Zr, int n) {
    constexpr int K = N_FEAT;   // 128
    constexpr int M = 2 * HID;  // 128
    constexpr int LDA = K + 8;
    constexpr int QROW = K / 8;
    __shared__ __align__(16) short At[64 * LDA];
    __shared__ __align__(16) short Bt[M * LDA];

    const int t = threadIdx.x;
    const int nodeBase = blockIdx.x * 64;

    for (int q = t; q < 64 * QROW; q += 256) {
        int row = q / QROW;
        int k0 = (q % QROW) * 8;
        int node = nodeBase + row;
        short8 s = {0, 0, 0, 0, 0, 0, 0, 0};
        if (node < n) {
            const float* A = x + (size_t)node * K + k0;
            float4 v0 = *(const float4*)A;
            float4 v1 = *(const float4*)(A + 4);
            s[0] = f2bf(v0.x); s[1] = f2bf(v0.y);
            s[2] = f2bf(v0.z); s[3] = f2bf(v0.w);
            s[4] = f2bf(v1.x); s[5] = f2bf(v1.y);
            s[6] = f2bf(v1.z); s[7] = f2bf(v1.w);
        }
        *(short8*)&At[row * LDA + k0] = s;
    }
    for (int q = t; q < M * QROW; q += 256) {
        int row = q / QROW;
        int k0 = (q % QROW) * 8;
        *(short8*)&Bt[row * LDA + k0] =
            *(const short8*)&wt1[(size_t)row * K + k0];
    }
    __syncthreads();

    const int wave = t >> 6;
    const int lane = t & 63;
    const int m0 = wave * 16;
    const int fl = lane & 15;
    const int quad = lane >> 4;

    floatx4 acc[M / 16];
#pragma unroll
    for (int nt = 0; nt < M / 16; ++nt) acc[nt] = (floatx4){0.f, 0.f, 0.f, 0.f};

#pragma unroll
    for (int ks = 0; ks < K / 32; ++ks) {
        const int kb = ks * 32 + quad * 8;
        short8 a = *(const short8*)&At[(m0 + fl) * LDA + kb];
#pragma unroll
        for (int nt = 0; nt < M / 16; ++nt) {
            short8 b = *(const short8*)&Bt[(nt * 16 + fl) * LDA + kb];
            acc[nt] = __builtin_amdgcn_mfma_f32_16x16x32_bf16(a, b, acc[nt], 0, 0, 0);
        }
    }

#pragma unroll
    for (int nt = 0; nt < M / 16; ++nt) {
        const int col = nt * 16 + fl;
#pragma unroll
        for (int r = 0; r < 4; ++r) {
            int node = nodeBase + m0 + quad * 4 + r;
            if (node < n) {
                unsigned short v = (unsigned short)f2bf(acc[nt][r]);
                if (col < HID)
                    Zl[(size_t)node * HID + col] = v;
                else
                    Zr[(size_t)node * HID + (col - HID)] = v;
            }
        }
    }
}

// ---------------------------------------------------------------------------
// k6: gemm2 (MFMA): h (bf16) -> zl2|zr2 split packed. K=64, M=80.
// ---------------------------------------------------------------------------
__global__ __launch_bounds__(256) void gemm2_mfma(
    const unsigned short* __restrict__ h, const unsigned short* __restrict__ wt2,
    unsigned short* __restrict__ Zl, unsigned short* __restrict__ Zr, int n) {
    constexpr int K = HID;       // 64
    constexpr int M = 2 * NCLS;  // 80
    constexpr int LDA = K + 8;
    constexpr int QROW = K / 8;
    __shared__ __align__(16) short At[64 * LDA];
    __shared__ __align__(16) short Bt[M * LDA];

    const int t = threadIdx.x;
    const int nodeBase = blockIdx.x * 64;

    for (int q = t; q < 64 * QROW; q += 256) {
        int row = q / QROW;
        int k0 = (q % QROW) * 8;
        int node = nodeBase + row;
        short8 s = {0, 0, 0, 0, 0, 0, 0, 0};
        if (node < n)
            s = *(const short8*)((const short*)h + (size_t)node * K + k0);
        *(short8*)&At[row * LDA + k0] = s;
    }
    for (int q = t; q < M * QROW; q += 256) {
        int row = q / QROW;
        int k0 = (q % QROW) * 8;
        *(short8*)&Bt[row * LDA + k0] =
            *(const short8*)&wt2[(size_t)row * K + k0];
    }
    __syncthreads();

    const int wave = t >> 6;
    const int lane = t & 63;
    const int m0 = wave * 16;
    const int fl = lane & 15;
    const int quad = lane >> 4;

    floatx4 acc[M / 16];
#pragma unroll
    for (int nt = 0; nt < M / 16; ++nt) acc[nt] = (floatx4){0.f, 0.f, 0.f, 0.f};

#pragma unroll
    for (int ks = 0; ks < K / 32; ++ks) {
        const int kb = ks * 32 + quad * 8;
        short8 a = *(const short8*)&At[(m0 + fl) * LDA + kb];
#pragma unroll
        for (int nt = 0; nt < M / 16; ++nt) {
            short8 b = *(const short8*)&Bt[(nt * 16 + fl) * LDA + kb];
            acc[nt] = __builtin_amdgcn_mfma_f32_16x16x32_bf16(a, b, acc[nt], 0, 0, 0);
        }
    }

#pragma unroll
    for (int nt = 0; nt < M / 16; ++nt) {
        const int col = nt * 16 + fl;
#pragma unroll
        for (int r = 0; r < 4; ++r) {
            int node = nodeBase + m0 + quad * 4 + r;
            if (node < n) {
                unsigned short v = (unsigned short)f2bf(acc[nt][r]);
                if (col < NCLS)
                    Zl[(size_t)node * NCLS + col] = v;
                else
                    Zr[(size_t)node * NCLS + (col - NCLS)] = v;
            }
        }
    }
}

// ---------------------------------------------------------------------------
// agg: one wave per node, lane = feature, 8-deep gather batches (max TLP).
// ---------------------------------------------------------------------------
template <int F, bool SIG, bool OUTBF>
__global__ void agg_kernel(const unsigned short* __restrict__ Zl,
                           const unsigned short* __restrict__ Zr,
                           const int* __restrict__ off,
                           const int* __restrict__ csr,
                           const float* __restrict__ bias,
                           void* __restrict__ out, int n) {
    const int node = blockIdx.x * (blockDim.x >> 6) + (threadIdx.x >> 6);
    const int lane = threadIdx.x & 63;
    if (node >= n) return;
    const int start = off[node];
    const int end = off[node + 1];
    if (lane < F) {
        float acc = 0.f;
        for (int e = start; e < end; e += 8) {
            int idx[8];
            float v[8];
#pragma unroll
            for (int i = 0; i < 8; ++i) {
                int ee = (e + i < end) ? (e + i) : (end - 1);
                idx[i] = csr[ee];
            }
#pragma unroll
            for (int i = 0; i < 8; ++i)
                v[i] = bf2f(Zl[(size_t)idx[i] * F + lane]);
#pragma unroll
            for (int i = 0; i < 8; ++i)
                acc += (e + i < end) ? v[i] : 0.f;
        }
        float inv = 1.0f / fmaxf((float)(end - start), 1.0f);
        float r = acc * inv + bf2f(Zr[(size_t)node * F + lane]) + bias[lane];
        if (SIG) r = 1.0f / (1.0f + __expf(-r));
        if (OUTBF)
            ((unsigned short*)out)[(size_t)node * F + lane] = (unsigned short)f2bf(r);
        else
            ((float*)out)[(size_t)node * F + lane] = r;
    }
}

// ---------------------------------------------------------------------------
extern "C" void kernel_launch(void* const* d_in, const int* in_sizes, int n_in,
                              void* d_out, int out_size, void* d_ws,
                              size_t ws_size, hipStream_t stream) {
    const float* x = (const float*)d_in[0];
    const int* ei = (const int*)d_in[1];
    const float* W1l = (const float*)d_in[2];
    const float* b1 = (const float*)d_in[3];
    const float* W1r = (const float*)d_in[4];
    const float* W2l = (const float*)d_in[5];
    const float* b2 = (const float*)d_in[6];
    const float* W2r = (const float*)d_in[7];
    float* out = (float*)d_out;

    const int n = in_sizes[0] / N_FEAT;  // 100000
    const int ne = in_sizes[1] / 2;      // 600000

    // ws: zl1|zr1 [n*64] | h [n*64] | zl2|zr2 [n*40] | wt1 | wt2 |
    //     deg | off | cursor | csr | flags
    unsigned short* zl1 = (unsigned short*)d_ws;
    unsigned short* zr1 = zl1 + (size_t)n * HID;
    unsigned short* h = zr1 + (size_t)n * HID;
    unsigned short* zl2 = h + (size_t)n * HID;
    unsigned short* zr2 = zl2 + (size_t)n * NCLS;
    unsigned short* wt1 = zr2 + (size_t)n * NCLS;
    unsigned short* wt2 = wt1 + 128 * 128;
    int* deg = (int*)(wt2 + 80 * 64);
    int* off = deg + n;
    int* cursor = off + (n + 1);
    int* csr = cursor + (n + 1);
    int* flags = csr + ne;

    const int nb = (n + 2047) / 2048;               // 49
    const int histB = (ne + 255) / 256;             // 2344
    const int prepB = (128 * 128 + 80 * 64) / 256;  // 84
    const int gB = (n + 63) / 64;                   // 1563
    const int aB = (n + 3) / 4;

    hipMemsetAsync(deg, 0, (size_t)n * sizeof(int), stream);
    hipMemsetAsync(flags, 0xAA, (size_t)nb * sizeof(int), stream);

    hist_prep<<<histB + prepB, 256, 0, stream>>>(ei, deg, ne, histB, W1l, W1r,
                                                 W2l, W2r, wt1, wt2);
    scan_chain<<<nb, 256, 0, stream>>>(deg, off, cursor, flags, n);
    fill_csr<<<(ne + 255) / 256, 256, 0, stream>>>(ei, cursor, csr, ne);
    gemm1_mfma<<<gB, 256, 0, stream>>>(x, wt1, zl1, zr1, n);
    agg_kernel<HID, true, true>
        <<<aB, 256, 0, stream>>>(zl1, zr1, off, csr, b1, h, n);
    gemm2_mfma<<<gB, 256, 0, stream>>>(h, wt2, zl2, zr2, n);
    agg_kernel<NCLS, false, false>
        <<<aB, 256, 0, stream>>>(zl2, zr2, off, csr, b2, out, n);
}

// Round 9
// 262.840 us; speedup vs baseline: 1.3891x; 1.1514x over previous
//
#include <hip/hip_runtime.h>
#include <hip/hip_bf16.h>

// GraphSAGE 2-layer forward — CSR-gather + bf16 MFMA (R9).
// R6: don't serialize latency-bound node-gathers behind block barriers.
// R7: don't fuse no-LDS scatter blocks into a 52KB-LDS kernel.
// R8: serial inter-block flag chains cost ~1us/hop on 8 XCDs (49us scan!).
// Fix: CSR segments need not be in node order -> per-block atomicAdd space
// reservation, per-node start[] + deg[] instead of a global ordered scan.

#define N_FEAT 128
#define HID 64
#define NCLS 40

typedef short short8 __attribute__((ext_vector_type(8)));
typedef float floatx4 __attribute__((ext_vector_type(4)));

static __device__ __forceinline__ short f2bf(float x) {
    __hip_bfloat16 h = __float2bfloat16(x);
    return __builtin_bit_cast(short, h);
}
static __device__ __forceinline__ float bf2f(unsigned short u) {
    unsigned int v = ((unsigned int)u) << 16;
    return __builtin_bit_cast(float, v);
}

// ---------------------------------------------------------------------------
// k1: histogram of dst degrees + weight transpose/cvt (no LDS -> safe fusion)
// ---------------------------------------------------------------------------
__global__ void hist_prep(const int* __restrict__ ei, int* __restrict__ deg,
                          int ne, int histBlocks,
                          const float* __restrict__ W1l, const float* __restrict__ W1r,
                          const float* __restrict__ W2l, const float* __restrict__ W2r,
                          unsigned short* __restrict__ wt1,
                          unsigned short* __restrict__ wt2) {
    if ((int)blockIdx.x < histBlocks) {
        int e = blockIdx.x * 256 + threadIdx.x;
        if (e < ne) atomicAdd(&deg[ei[ne + e]], 1);
    } else {
        int i = (blockIdx.x - histBlocks) * 256 + threadIdx.x;
        if (i < 128 * 128) {
            int nn = i >> 7, k = i & 127;
            float v = (nn < 64) ? W1l[k * 64 + nn] : W1r[k * 64 + (nn - 64)];
            wt1[nn * 128 + k] = (unsigned short)f2bf(v);
        } else if (i < 128 * 128 + 80 * 64) {
            int j = i - 128 * 128;
            int nn = j >> 6, k = j & 63;
            float v = (nn < 40) ? W2l[k * 40 + nn] : W2r[k * 40 + (nn - 40)];
            wt2[nn * 64 + k] = (unsigned short)f2bf(v);
        }
    }
}

// ---------------------------------------------------------------------------
// k2: parallel segment allocation. Block scans its 2048 degrees locally,
// reserves a span with ONE atomicAdd (segments in arrival order — CSR only
// needs per-node contiguity, not global node order). No inter-block chain.
// ---------------------------------------------------------------------------
__global__ void scan_atomic(const int* __restrict__ deg, int* __restrict__ start,
                            int* __restrict__ cursor, int* __restrict__ counter,
                            int n) {
    __shared__ int lds[256];
    __shared__ int sbase;
    const int b = blockIdx.x, t = threadIdx.x;
    const int base = b * 2048 + t * 8;
    int v[8], s = 0;
#pragma unroll
    for (int i = 0; i < 8; ++i) {
        int idx = base + i;
        v[i] = (idx < n) ? deg[idx] : 0;
        s += v[i];
    }
    lds[t] = s;
    __syncthreads();
    for (int o = 1; o < 256; o <<= 1) {
        int y = (t >= o) ? lds[t - o] : 0;
        __syncthreads();
        lds[t] += y;
        __syncthreads();
    }
    if (t == 0) sbase = atomicAdd(counter, lds[255]);
    __syncthreads();
    int run = sbase + ((t == 0) ? 0 : lds[t - 1]);
#pragma unroll
    for (int i = 0; i < 8; ++i) {
        int idx = base + i;
        if (idx < n) {
            start[idx] = run;
            cursor[idx] = run;
        }
        run += v[i];
    }
}

// ---------------------------------------------------------------------------
// k3: fill CSR (standalone: 8 VGPR, no LDS, full occupancy)
// ---------------------------------------------------------------------------
__global__ void fill_csr(const int* __restrict__ ei, int* __restrict__ cursor,
                         int* __restrict__ csr, int ne) {
    int e = blockIdx.x * blockDim.x + threadIdx.x;
    if (e < ne) {
        int d = ei[ne + e];
        int p = atomicAdd(&cursor[d], 1);
        csr[p] = ei[e];
    }
}

// ---------------------------------------------------------------------------
// k4: gemm1 (MFMA): x (fp32, inline cvt) -> zl1|zr1 split packed bf16.
// ---------------------------------------------------------------------------
__global__ __launch_bounds__(256) void gemm1_mfma(
    const float* __restrict__ x, const unsigned short* __restrict__ wt1,
    unsigned short* __restrict__ Zl, unsigned short* __restrict__ Zr, int n) {
    constexpr int K = N_FEAT;   // 128
    constexpr int M = 2 * HID;  // 128
    constexpr int LDA = K + 8;
    constexpr int QROW = K / 8;
    __shared__ __align__(16) short At[64 * LDA];
    __shared__ __align__(16) short Bt[M * LDA];

    const int t = threadIdx.x;
    const int nodeBase = blockIdx.x * 64;

    for (int q = t; q < 64 * QROW; q += 256) {
        int row = q / QROW;
        int k0 = (q % QROW) * 8;
        int node = nodeBase + row;
        short8 s = {0, 0, 0, 0, 0, 0, 0, 0};
        if (node < n) {
            const float* A = x + (size_t)node * K + k0;
            float4 v0 = *(const float4*)A;
            float4 v1 = *(const float4*)(A + 4);
            s[0] = f2bf(v0.x); s[1] = f2bf(v0.y);
            s[2] = f2bf(v0.z); s[3] = f2bf(v0.w);
            s[4] = f2bf(v1.x); s[5] = f2bf(v1.y);
            s[6] = f2bf(v1.z); s[7] = f2bf(v1.w);
        }
        *(short8*)&At[row * LDA + k0] = s;
    }
    for (int q = t; q < M * QROW; q += 256) {
        int row = q / QROW;
        int k0 = (q % QROW) * 8;
        *(short8*)&Bt[row * LDA + k0] =
            *(const short8*)&wt1[(size_t)row * K + k0];
    }
    __syncthreads();

    const int wave = t >> 6;
    const int lane = t & 63;
    const int m0 = wave * 16;
    const int fl = lane & 15;
    const int quad = lane >> 4;

    floatx4 acc[M / 16];
#pragma unroll
    for (int nt = 0; nt < M / 16; ++nt) acc[nt] = (floatx4){0.f, 0.f, 0.f, 0.f};

#pragma unroll
    for (int ks = 0; ks < K / 32; ++ks) {
        const int kb = ks * 32 + quad * 8;
        short8 a = *(const short8*)&At[(m0 + fl) * LDA + kb];
#pragma unroll
        for (int nt = 0; nt < M / 16; ++nt) {
            short8 b = *(const short8*)&Bt[(nt * 16 + fl) * LDA + kb];
            acc[nt] = __builtin_amdgcn_mfma_f32_16x16x32_bf16(a, b, acc[nt], 0, 0, 0);
        }
    }

#pragma unroll
    for (int nt = 0; nt < M / 16; ++nt) {
        const int col = nt * 16 + fl;
#pragma unroll
        for (int r = 0; r < 4; ++r) {
            int node = nodeBase + m0 + quad * 4 + r;
            if (node < n) {
                unsigned short v = (unsigned short)f2bf(acc[nt][r]);
                if (col < HID)
                    Zl[(size_t)node * HID + col] = v;
                else
                    Zr[(size_t)node * HID + (col - HID)] = v;
            }
        }
    }
}

// ---------------------------------------------------------------------------
// k6: gemm2 (MFMA): h (bf16) -> zl2|zr2 split packed. K=64, M=80.
// ---------------------------------------------------------------------------
__global__ __launch_bounds__(256) void gemm2_mfma(
    const unsigned short* __restrict__ h, const unsigned short* __restrict__ wt2,
    unsigned short* __restrict__ Zl, unsigned short* __restrict__ Zr, int n) {
    constexpr int K = HID;       // 64
    constexpr int M = 2 * NCLS;  // 80
    constexpr int LDA = K + 8;
    constexpr int QROW = K / 8;
    __shared__ __align__(16) short At[64 * LDA];
    __shared__ __align__(16) short Bt[M * LDA];

    const int t = threadIdx.x;
    const int nodeBase = blockIdx.x * 64;

    for (int q = t; q < 64 * QROW; q += 256) {
        int row = q / QROW;
        int k0 = (q % QROW) * 8;
        int node = nodeBase + row;
        short8 s = {0, 0, 0, 0, 0, 0, 0, 0};
        if (node < n)
            s = *(const short8*)((const short*)h + (size_t)node * K + k0);
        *(short8*)&At[row * LDA + k0] = s;
    }
    for (int q = t; q < M * QROW; q += 256) {
        int row = q / QROW;
        int k0 = (q % QROW) * 8;
        *(short8*)&Bt[row * LDA + k0] =
            *(const short8*)&wt2[(size_t)row * K + k0];
    }
    __syncthreads();

    const int wave = t >> 6;
    const int lane = t & 63;
    const int m0 = wave * 16;
    const int fl = lane & 15;
    const int quad = lane >> 4;

    floatx4 acc[M / 16];
#pragma unroll
    for (int nt = 0; nt < M / 16; ++nt) acc[nt] = (floatx4){0.f, 0.f, 0.f, 0.f};

#pragma unroll
    for (int ks = 0; ks < K / 32; ++ks) {
        const int kb = ks * 32 + quad * 8;
        short8 a = *(const short8*)&At[(m0 + fl) * LDA + kb];
#pragma unroll
        for (int nt = 0; nt < M / 16; ++nt) {
            short8 b = *(const short8*)&Bt[(nt * 16 + fl) * LDA + kb];
            acc[nt] = __builtin_amdgcn_mfma_f32_16x16x32_bf16(a, b, acc[nt], 0, 0, 0);
        }
    }

#pragma unroll
    for (int nt = 0; nt < M / 16; ++nt) {
        const int col = nt * 16 + fl;
#pragma unroll
        for (int r = 0; r < 4; ++r) {
            int node = nodeBase + m0 + quad * 4 + r;
            if (node < n) {
                unsigned short v = (unsigned short)f2bf(acc[nt][r]);
                if (col < NCLS)
                    Zl[(size_t)node * NCLS + col] = v;
                else
                    Zr[(size_t)node * NCLS + (col - NCLS)] = v;
            }
        }
    }
}

// ---------------------------------------------------------------------------
// agg: one wave per node, lane = feature, 8-deep gather batches (max TLP).
// Segment = [start[node], start[node]+deg[node]).
// ---------------------------------------------------------------------------
template <int F, bool SIG, bool OUTBF>
__global__ void agg_kernel(const unsigned short* __restrict__ Zl,
                           const unsigned short* __restrict__ Zr,
                           const int* __restrict__ startArr,
                           const int* __restrict__ degArr,
                           const int* __restrict__ csr,
                           const float* __restrict__ bias,
                           void* __restrict__ out, int n) {
    const int node = blockIdx.x * (blockDim.x >> 6) + (threadIdx.x >> 6);
    const int lane = threadIdx.x & 63;
    if (node >= n) return;
    const int start = startArr[node];
    const int d = degArr[node];
    const int end = start + d;
    if (lane < F) {
        float acc = 0.f;
        for (int e = start; e < end; e += 8) {
            int idx[8];
            float v[8];
#pragma unroll
            for (int i = 0; i < 8; ++i) {
                int ee = (e + i < end) ? (e + i) : (end - 1);
                idx[i] = csr[ee];
            }
#pragma unroll
            for (int i = 0; i < 8; ++i)
                v[i] = bf2f(Zl[(size_t)idx[i] * F + lane]);
#pragma unroll
            for (int i = 0; i < 8; ++i)
                acc += (e + i < end) ? v[i] : 0.f;
        }
        float inv = 1.0f / fmaxf((float)d, 1.0f);
        float r = acc * inv + bf2f(Zr[(size_t)node * F + lane]) + bias[lane];
        if (SIG) r = 1.0f / (1.0f + __expf(-r));
        if (OUTBF)
            ((unsigned short*)out)[(size_t)node * F + lane] = (unsigned short)f2bf(r);
        else
            ((float*)out)[(size_t)node * F + lane] = r;
    }
}

// ---------------------------------------------------------------------------
extern "C" void kernel_launch(void* const* d_in, const int* in_sizes, int n_in,
                              void* d_out, int out_size, void* d_ws,
                              size_t ws_size, hipStream_t stream) {
    const float* x = (const float*)d_in[0];
    const int* ei = (const int*)d_in[1];
    const float* W1l = (const float*)d_in[2];
    const float* b1 = (const float*)d_in[3];
    const float* W1r = (const float*)d_in[4];
    const float* W2l = (const float*)d_in[5];
    const float* b2 = (const float*)d_in[6];
    const float* W2r = (const float*)d_in[7];
    float* out = (float*)d_out;

    const int n = in_sizes[0] / N_FEAT;  // 100000
    const int ne = in_sizes[1] / 2;      // 600000

    // ws: zl1|zr1 [n*64] | h [n*64] | zl2|zr2 [n*40] | wt1 | wt2 |
    //     deg[n] | counter[1] | start[n] | cursor[n] | csr[ne]
    unsigned short* zl1 = (unsigned short*)d_ws;
    unsigned short* zr1 = zl1 + (size_t)n * HID;
    unsigned short* h = zr1 + (size_t)n * HID;
    unsigned short* zl2 = h + (size_t)n * HID;
    unsigned short* zr2 = zl2 + (size_t)n * NCLS;
    unsigned short* wt1 = zr2 + (size_t)n * NCLS;
    unsigned short* wt2 = wt1 + 128 * 128;
    int* deg = (int*)(wt2 + 80 * 64);
    int* counter = deg + n;
    int* start = counter + 1;
    int* cursor = start + n;
    int* csr = cursor + n;

    const int nb = (n + 2047) / 2048;               // 49
    const int histB = (ne + 255) / 256;             // 2344
    const int prepB = (128 * 128 + 80 * 64) / 256;  // 84
    const int gB = (n + 63) / 64;                   // 1563
    const int aB = (n + 3) / 4;

    hipMemsetAsync(deg, 0, (size_t)(n + 1) * sizeof(int), stream);  // deg+counter

    hist_prep<<<histB + prepB, 256, 0, stream>>>(ei, deg, ne, histB, W1l, W1r,
                                                 W2l, W2r, wt1, wt2);
    scan_atomic<<<nb, 256, 0, stream>>>(deg, start, cursor, counter, n);
    fill_csr<<<(ne + 255) / 256, 256, 0, stream>>>(ei, cursor, csr, ne);
    gemm1_mfma<<<gB, 256, 0, stream>>>(x, wt1, zl1, zr1, n);
    agg_kernel<HID, true, true>
        <<<aB, 256, 0, stream>>>(zl1, zr1, start, deg, csr, b1, h, n);
    gemm2_mfma<<<gB, 256, 0, stream>>>(h, wt2, zl2, zr2, n);
    agg_kernel<NCLS, false, false>
        <<<aB, 256, 0, stream>>>(zl2, zr2, start, deg, csr, b2, out, n);
}